// Round 1
// baseline (277.592 us; speedup 1.0000x reference)
//
#include <hip/hip_runtime.h>
#include <math.h>

#define IMG   256
#define DETN  362
#define NFULL 177
#define NACQ  45
#define PAD   1024

// Kernel 1: fused radon + data-consistency + ramp filter.
// One block per (b, a). Thread T owns detector bin T: sums 362 bilinear
// samples along the ray, applies s_target - s at acquired angles, stages the
// column in LDS, then computes the circular convolution with g = 2f.
__global__ __launch_bounds__(384) void radon_dc_filter_kernel(
    const float* __restrict__ x,       // (2,1,256,256)
    const float* __restrict__ st,      // (2,1,362,45)
    const float* __restrict__ thetas,  // (177)
    const int*   __restrict__ acq,     // (45)
    float* __restrict__ sf)            // out: (2,177,362)
{
    const int blk = blockIdx.x;        // b*NFULL + a
    const int b = blk / NFULL;
    const int a = blk - b * NFULL;
    const int tid = threadIdx.x;

    __shared__ float col[DETN];
    __shared__ float gf[PAD];
    __shared__ float s_cs[2];

    // Build spatial ramp kernel g[n] = 2*f[n] in LDS.
    for (int n = tid; n < PAD; n += blockDim.x) {
        float v = 0.0f;
        if (n == 0) {
            v = 0.5f;
        } else if (n & 1) {
            int d = (n < PAD - n) ? n : (PAD - n);
            double pd = M_PI * (double)d;
            v = (float)(-2.0 / (pd * pd));
        }
        gf[n] = v;
    }
    if (tid == 0) {
        float th = thetas[a] * (float)(M_PI / 180.0);
        s_cs[0] = cosf(th);
        s_cs[1] = sinf(th);
    }
    __syncthreads();
    const float c = s_cs[0];
    const float s = s_cs[1];

    // inverse acq lookup (broadcast loads, 45 iters)
    int inv = -1;
    for (int i = 0; i < NACQ; ++i) {
        if (acq[i] == a) inv = i;
    }

    const float* __restrict__ img = x + b * IMG * IMG;
    const int T = tid;
    if (T < DETN) {
        const float tval  = (float)T - (DETN - 1) * 0.5f;
        const float xbase = tval * c + (IMG - 1) * 0.5f;
        const float ybase = tval * s + (IMG - 1) * 0.5f;
        float val = 0.0f;
        for (int S = 0; S < DETN; ++S) {
            const float sval = (float)S - (DETN - 1) * 0.5f;
            const float xs = xbase - sval * s;
            const float ys = ybase + sval * c;
            const float x0f = floorf(xs);
            const float y0f = floorf(ys);
            const float wx = xs - x0f;
            const float wy = ys - y0f;
            const int x0 = (int)x0f;
            const int y0 = (int)y0f;
            const bool xv0 = (x0 >= 0)     && (x0 < IMG);
            const bool xv1 = (x0 + 1 >= 0) && (x0 + 1 < IMG);
            const bool yv0 = (y0 >= 0)     && (y0 < IMG);
            const bool yv1 = (y0 + 1 >= 0) && (y0 + 1 < IMG);
            float v00 = 0.f, v01 = 0.f, v10 = 0.f, v11 = 0.f;
            if (yv0) {
                const float* row = img + y0 * IMG;
                if (xv0) v00 = row[x0];
                if (xv1) v01 = row[x0 + 1];
            }
            if (yv1) {
                const float* row = img + (y0 + 1) * IMG;
                if (xv0) v10 = row[x0];
                if (xv1) v11 = row[x0 + 1];
            }
            val += (v00 * (1.0f - wx) + v01 * wx) * (1.0f - wy)
                 + (v10 * (1.0f - wx) + v11 * wx) * wy;
        }
        if (inv >= 0) {
            val = st[(b * DETN + T) * NACQ + inv] - val;
        }
        col[T] = val;
    }
    __syncthreads();
    if (T < DETN) {
        float acc = 0.0f;
        for (int m = 0; m < DETN; ++m) {
            acc += col[m] * gf[(T - m) & (PAD - 1)];
        }
        sf[(b * NFULL + a) * DETN + T] = acc;
    }
}

// Kernel 2: filtered backprojection. One thread per output pixel.
__global__ __launch_bounds__(256) void backproject_kernel(
    const float* __restrict__ sf,      // (2,177,362)
    const float* __restrict__ thetas,  // (177)
    float* __restrict__ out)           // (2,1,256,256)
{
    __shared__ float cs[NFULL];
    __shared__ float sn[NFULL];
    const int tid = threadIdx.x;
    for (int a = tid; a < NFULL; a += blockDim.x) {
        float th = thetas[a] * (float)(M_PI / 180.0);
        cs[a] = cosf(th);
        sn[a] = sinf(th);
    }
    __syncthreads();

    const int pix = blockIdx.x * blockDim.x + tid;  // b*65536 + y*256 + x
    const int b = pix >> 16;
    const int y = (pix >> 8) & 255;
    const int xq = pix & 255;
    const float gx = (float)xq - (IMG - 1) * 0.5f;
    const float gy = (float)y  - (IMG - 1) * 0.5f;
    const float* __restrict__ sfb = sf + b * NFULL * DETN;

    float acc = 0.0f;
    for (int a = 0; a < NFULL; ++a) {
        const float t = cs[a] * gx + sn[a] * gy + (DETN - 1) * 0.5f;
        const float t0f = floorf(t);
        const float w = t - t0f;
        const int t0 = (int)t0f;
        const float* row = sfb + a * DETN;
        const float v0 = (t0 >= 0 && t0 < DETN)         ? row[t0]     : 0.0f;
        const float v1 = (t0 + 1 >= 0 && t0 + 1 < DETN) ? row[t0 + 1] : 0.0f;
        acc += v0 * (1.0f - w) + v1 * w;
    }
    out[pix] = acc * (float)(M_PI / (2.0 * NFULL));
}

extern "C" void kernel_launch(void* const* d_in, const int* in_sizes, int n_in,
                              void* d_out, int out_size, void* d_ws, size_t ws_size,
                              hipStream_t stream) {
    const float* x      = (const float*)d_in[0];   // x_source (2,1,256,256)
    const float* st     = (const float*)d_in[1];   // s_target (2,1,362,45)
    const float* thetas = (const float*)d_in[2];   // thetas_deg (177)
    const int*   acq    = (const int*)d_in[3];     // acq_idx (45)
    float* out = (float*)d_out;                    // (2,1,256,256) fp32
    float* sf  = (float*)d_ws;                     // (2,177,362) fp32 = 512 KB

    radon_dc_filter_kernel<<<2 * NFULL, 384, 0, stream>>>(x, st, thetas, acq, sf);
    backproject_kernel<<<(2 * IMG * IMG) / 256, 256, 0, stream>>>(sf, thetas, out);
}

// Round 2
// 220.937 us; speedup vs baseline: 1.2564x; 1.2564x over previous
//
#include <hip/hip_runtime.h>
#include <math.h>

#define IMG   256
#define DETN  362
#define NFULL 177
#define NACQ  45
#define PAD   1024
#define SCH   4     // S-chunks for radon
#define ACH   4     // angle-chunks for backprojection

// ws layout (floats): [0 .. 131071] sino (raw radon sums, atomically accumulated)
//                     [131072 .. 262143] sf (filtered sinogram)
#define SINO_OFF 0
#define SF_OFF   131072

// Kernel A: radon partial sums. grid (2*NFULL, SCH), block 384.
// Thread T accumulates its S-chunk of the ray integral, atomicAdd into sino.
__global__ __launch_bounds__(384) void radon_partial_kernel(
    const float* __restrict__ x,       // (2,1,256,256)
    const float* __restrict__ thetas,  // (177)
    float* __restrict__ sino)          // (2,177,362) zero-initialized
{
    const int blk = blockIdx.x;        // b*NFULL + a
    const int b = blk / NFULL;
    const int a = blk - b * NFULL;
    const int chunk = blockIdx.y;
    const int tid = threadIdx.x;

    __shared__ float s_cs[2];
    if (tid == 0) {
        float th = thetas[a] * (float)(M_PI / 180.0);
        s_cs[0] = cosf(th);
        s_cs[1] = sinf(th);
    }
    __syncthreads();
    const float c = s_cs[0];
    const float s = s_cs[1];

    const float* __restrict__ img = x + b * IMG * IMG;
    const int T = tid;
    if (T >= DETN) return;

    const float tval  = (float)T - (DETN - 1) * 0.5f;
    const float xbase = tval * c + (IMG - 1) * 0.5f;
    const float ybase = tval * s + (IMG - 1) * 0.5f;

    const int s_begin = chunk * ((DETN + SCH - 1) / SCH);           // 91
    const int s_end   = min(DETN, s_begin + (DETN + SCH - 1) / SCH);

    float val = 0.0f;
    for (int S = s_begin; S < s_end; ++S) {
        const float sval = (float)S - (DETN - 1) * 0.5f;
        const float xs = xbase - sval * s;
        const float ys = ybase + sval * c;
        const float x0f = floorf(xs);
        const float y0f = floorf(ys);
        const float wx = xs - x0f;
        const float wy = ys - y0f;
        const int x0 = (int)x0f;
        const int y0 = (int)y0f;
        const bool xv0 = ((unsigned)x0 < IMG);
        const bool xv1 = ((unsigned)(x0 + 1) < IMG);
        const bool yv0 = ((unsigned)y0 < IMG);
        const bool yv1 = ((unsigned)(y0 + 1) < IMG);
        float v00 = 0.f, v01 = 0.f, v10 = 0.f, v11 = 0.f;
        if (yv0) {
            const float* row = img + y0 * IMG;
            if (xv0) v00 = row[x0];
            if (xv1) v01 = row[x0 + 1];
        }
        if (yv1) {
            const float* row = img + (y0 + 1) * IMG;
            if (xv0) v10 = row[x0];
            if (xv1) v11 = row[x0 + 1];
        }
        val += (v00 * (1.0f - wx) + v01 * wx) * (1.0f - wy)
             + (v10 * (1.0f - wx) + v11 * wx) * wy;
    }
    atomicAdd(&sino[(b * NFULL + a) * DETN + T], val);
}

// Kernel B: data-consistency + ramp filter. One block per (b,a).
__global__ __launch_bounds__(384) void dc_filter_kernel(
    const float* __restrict__ sino,    // (2,177,362)
    const float* __restrict__ st,      // (2,1,362,45)
    const int*   __restrict__ acq,     // (45)
    float* __restrict__ sf)            // (2,177,362)
{
    const int blk = blockIdx.x;
    const int b = blk / NFULL;
    const int a = blk - b * NFULL;
    const int tid = threadIdx.x;

    __shared__ float col[DETN];
    __shared__ float gf[PAD];

    for (int n = tid; n < PAD; n += blockDim.x) {
        float v = 0.0f;
        if (n == 0) {
            v = 0.5f;
        } else if (n & 1) {
            int d = (n < PAD - n) ? n : (PAD - n);
            double pd = M_PI * (double)d;
            v = (float)(-2.0 / (pd * pd));
        }
        gf[n] = v;
    }

    int inv = -1;
    for (int i = 0; i < NACQ; ++i) {
        if (acq[i] == a) inv = i;
    }

    const int T = tid;
    if (T < DETN) {
        float val = sino[(b * NFULL + a) * DETN + T];
        if (inv >= 0) {
            val = st[(b * DETN + T) * NACQ + inv] - val;
        }
        col[T] = val;
    }
    __syncthreads();
    if (T < DETN) {
        float acc = 0.0f;
        for (int m = 0; m < DETN; ++m) {
            acc += col[m] * gf[(T - m) & (PAD - 1)];
        }
        sf[(b * NFULL + a) * DETN + T] = acc;
    }
}

// Kernel C: backprojection, angle-chunked. grid (512, ACH), block 256.
__global__ __launch_bounds__(256) void backproject_kernel(
    const float* __restrict__ sf,      // (2,177,362)
    const float* __restrict__ thetas,  // (177)
    float* __restrict__ out)           // (2,1,256,256) zero-initialized
{
    __shared__ float cs[NFULL];
    __shared__ float sn[NFULL];
    const int tid = threadIdx.x;
    for (int a = tid; a < NFULL; a += blockDim.x) {
        float th = thetas[a] * (float)(M_PI / 180.0);
        cs[a] = cosf(th);
        sn[a] = sinf(th);
    }
    __syncthreads();

    const int pix = blockIdx.x * blockDim.x + tid;  // b*65536 + y*256 + x
    const int b = pix >> 16;
    const int y = (pix >> 8) & 255;
    const int xq = pix & 255;
    const float gx = (float)xq - (IMG - 1) * 0.5f;
    const float gy = (float)y  - (IMG - 1) * 0.5f;
    const float* __restrict__ sfb = sf + b * NFULL * DETN;

    const int a_begin = blockIdx.y * ((NFULL + ACH - 1) / ACH);      // 45
    const int a_end   = min(NFULL, a_begin + (NFULL + ACH - 1) / ACH);

    float acc = 0.0f;
    for (int a = a_begin; a < a_end; ++a) {
        const float t = cs[a] * gx + sn[a] * gy + (DETN - 1) * 0.5f;
        const float t0f = floorf(t);
        const float w = t - t0f;
        const int t0 = (int)t0f;
        const float* row = sfb + a * DETN;
        const float v0 = ((unsigned)t0 < DETN)       ? row[t0]     : 0.0f;
        const float v1 = ((unsigned)(t0 + 1) < DETN) ? row[t0 + 1] : 0.0f;
        acc += v0 * (1.0f - w) + v1 * w;
    }
    atomicAdd(&out[pix], acc * (float)(M_PI / (2.0 * NFULL)));
}

extern "C" void kernel_launch(void* const* d_in, const int* in_sizes, int n_in,
                              void* d_out, int out_size, void* d_ws, size_t ws_size,
                              hipStream_t stream) {
    const float* x      = (const float*)d_in[0];   // x_source (2,1,256,256)
    const float* st     = (const float*)d_in[1];   // s_target (2,1,362,45)
    const float* thetas = (const float*)d_in[2];   // thetas_deg (177)
    const int*   acq    = (const int*)d_in[3];     // acq_idx (45)
    float* out  = (float*)d_out;                   // (2,1,256,256) fp32
    float* wsf  = (float*)d_ws;
    float* sino = wsf + SINO_OFF;
    float* sf   = wsf + SF_OFF;

    // Zero accumulation targets (re-poisoned to 0xAA before every timed call).
    hipMemsetAsync(sino, 0, (size_t)SF_OFF * sizeof(float), stream);
    hipMemsetAsync(out, 0, (size_t)out_size * sizeof(float), stream);

    dim3 gA(2 * NFULL, SCH);
    radon_partial_kernel<<<gA, 384, 0, stream>>>(x, thetas, sino);
    dc_filter_kernel<<<2 * NFULL, 384, 0, stream>>>(sino, st, acq, sf);
    dim3 gC((2 * IMG * IMG) / 256, ACH);
    backproject_kernel<<<gC, 256, 0, stream>>>(sf, thetas, out);
}

// Round 3
// 169.229 us; speedup vs baseline: 1.6403x; 1.3056x over previous
//
#include <hip/hip_runtime.h>
#include <math.h>

#define IMG   256
#define DETN  362
#define NFULL 177
#define NACQ  45
#define PAD   1024

// ws layout (floats): [0,131072) sino ; [131072,262144) sf
#define SINO_OFF 0
#define SF_OFF   131072

// ---------------------------------------------------------------------------
// Kernel A: radon. grid (2*NFULL, 23), block 128 = 16 T-rays x 8 S-phases.
// Each 8-lane group owns one detector bin T and strides S by 8 over the
// analytically clipped valid interval; shuffle-reduce; plain store (no atomics).
__global__ __launch_bounds__(128) void radon_kernel(
    const float* __restrict__ x,       // (2,1,256,256)
    const float* __restrict__ thetas,  // (177)
    float* __restrict__ sino)          // (2,177,362)
{
    const int blk = blockIdx.x;        // b*NFULL + a
    const int b = blk / NFULL;
    const int a = blk - b * NFULL;
    const int tid = threadIdx.x;
    const int ts = tid & 7;            // S phase
    const int tt = tid >> 3;           // T within tile
    const int T = blockIdx.y * 16 + tt;

    const float th = thetas[a] * (float)(M_PI / 180.0);
    const float c = cosf(th);
    const float s = sinf(th);

    const float* __restrict__ img = x + b * IMG * IMG;
    const float Tc = (float)T - (DETN - 1) * 0.5f;
    const float xbase = Tc * c + (IMG - 1) * 0.5f;   // u = xbase - sval*s
    const float ybase = Tc * s + (IMG - 1) * 0.5f;   // v = ybase + sval*c

    // Clip sval so the 4-tap footprint can intersect [-1,256)^2.
    float lo = -1e30f, hi = 1e30f;
    bool empty = (T >= DETN);
    // xs = xbase + sval*(-s) in (-1,256)
    {
        const float aa = -s;
        if (aa > 1e-5f)       { lo = fmaxf(lo, (-1.0f - xbase) / aa); hi = fminf(hi, (256.0f - xbase) / aa); }
        else if (aa < -1e-5f) { lo = fmaxf(lo, (256.0f - xbase) / aa); hi = fminf(hi, (-1.0f - xbase) / aa); }
        else if (xbase <= -1.0f || xbase >= 256.0f) empty = true;
    }
    // ys = ybase + sval*c in (-1,256)
    {
        const float aa = c;
        if (aa > 1e-5f)       { lo = fmaxf(lo, (-1.0f - ybase) / aa); hi = fminf(hi, (256.0f - ybase) / aa); }
        else if (aa < -1e-5f) { lo = fmaxf(lo, (256.0f - ybase) / aa); hi = fminf(hi, (-1.0f - ybase) / aa); }
        else if (ybase <= -1.0f || ybase >= 256.0f) empty = true;
    }
    lo = fmaxf(lo, -200.0f);           // keep int conversion in range
    hi = fminf(hi, 200.0f);
    int Slo = max(0, (int)floorf(lo + (DETN - 1) * 0.5f) - 1);   // margin 1: per-tap
    int Shi = min(DETN, (int)floorf(hi + (DETN - 1) * 0.5f) + 2); // checks stay exact
    if (empty || Shi < Slo) { Slo = 0; Shi = 0; }

    float val = 0.0f;
    #pragma unroll 2
    for (int S = Slo + ts; S < Shi; S += 8) {
        const float sval = (float)S - (DETN - 1) * 0.5f;
        const float xs = xbase - sval * s;
        const float ys = ybase + sval * c;
        const float x0f = floorf(xs);
        const float y0f = floorf(ys);
        const float wx = xs - x0f;
        const float wy = ys - y0f;
        const int x0 = (int)x0f;
        const int y0 = (int)y0f;
        const bool xv0 = ((unsigned)x0 < IMG);
        const bool xv1 = ((unsigned)(x0 + 1) < IMG);
        const bool yv0 = ((unsigned)y0 < IMG);
        const bool yv1 = ((unsigned)(y0 + 1) < IMG);
        float v00 = 0.f, v01 = 0.f, v10 = 0.f, v11 = 0.f;
        if (yv0) {
            const float* row = img + y0 * IMG;
            if (xv0) v00 = row[x0];
            if (xv1) v01 = row[x0 + 1];
        }
        if (yv1) {
            const float* row = img + (y0 + 1) * IMG;
            if (xv0) v10 = row[x0];
            if (xv1) v11 = row[x0 + 1];
        }
        val += (v00 * (1.0f - wx) + v01 * wx) * (1.0f - wy)
             + (v10 * (1.0f - wx) + v11 * wx) * wy;
    }
    // reduce the 8 S-phase lanes (contiguous lanes, width-8 butterfly)
    val += __shfl_xor(val, 1, 8);
    val += __shfl_xor(val, 2, 8);
    val += __shfl_xor(val, 4, 8);
    if (ts == 0 && T < DETN) {
        sino[(b * NFULL + a) * DETN + T] = val;
    }
}

// ---------------------------------------------------------------------------
// Kernel B: data-consistency + ramp filter (scale pi/(2A) folded in).
__global__ __launch_bounds__(384) void dc_filter_kernel(
    const float* __restrict__ sino,    // (2,177,362)
    const float* __restrict__ st,      // (2,1,362,45)
    const int*   __restrict__ acq,     // (45)
    float* __restrict__ sf)            // (2,177,362), pre-scaled
{
    const int blk = blockIdx.x;
    const int b = blk / NFULL;
    const int a = blk - b * NFULL;
    const int tid = threadIdx.x;

    __shared__ float col[DETN];
    __shared__ float gf[PAD];

    const double SC = M_PI / (2.0 * NFULL);
    for (int n = tid; n < PAD; n += blockDim.x) {
        float v = 0.0f;
        if (n == 0) {
            v = (float)(0.5 * SC);
        } else if (n & 1) {
            int d = (n < PAD - n) ? n : (PAD - n);
            double pd = M_PI * (double)d;
            v = (float)(-2.0 / (pd * pd) * SC);
        }
        gf[n] = v;
    }

    int inv = -1;
    for (int i = 0; i < NACQ; ++i) {
        if (acq[i] == a) inv = i;
    }

    const int T = tid;
    if (T < DETN) {
        float val = sino[(b * NFULL + a) * DETN + T];
        if (inv >= 0) {
            val = st[(b * DETN + T) * NACQ + inv] - val;
        }
        col[T] = val;
    }
    __syncthreads();
    if (T < DETN) {
        float acc = 0.0f;
        #pragma unroll 4
        for (int m = 0; m < DETN; ++m) {
            acc += col[m] * gf[(T - m) & (PAD - 1)];
        }
        sf[(b * NFULL + a) * DETN + T] = acc;
    }
}

// ---------------------------------------------------------------------------
// Kernel C: backprojection. grid 2048, block 256 = 64 pixels x 4 angle-phases.
// LDS reduce across phases; plain store (no atomics, no memset).
__global__ __launch_bounds__(256) void backproject_kernel(
    const float* __restrict__ sf,      // (2,177,362) pre-scaled
    const float* __restrict__ thetas,  // (177)
    float* __restrict__ out)           // (2,1,256,256)
{
    __shared__ float cs[NFULL];
    __shared__ float sn[NFULL];
    __shared__ float red[256];
    const int tid = threadIdx.x;
    for (int a = tid; a < NFULL; a += 256) {
        float th = thetas[a] * (float)(M_PI / 180.0);
        cs[a] = cosf(th);
        sn[a] = sinf(th);
    }
    __syncthreads();

    const int lane  = tid & 63;
    const int phase = tid >> 6;
    const int pix = blockIdx.x * 64 + lane;          // b*65536 + y*256 + x
    const int b = pix >> 16;
    const int y = (pix >> 8) & 255;
    const int xq = pix & 255;
    const float gx = (float)xq - (IMG - 1) * 0.5f;
    const float gy = (float)y  - (IMG - 1) * 0.5f;
    const float* __restrict__ sfb = sf + b * NFULL * DETN;

    float acc = 0.0f;
    #pragma unroll 4
    for (int a = phase; a < NFULL; a += 4) {
        const float t = cs[a] * gx + sn[a] * gy + (DETN - 1) * 0.5f;
        const float t0f = floorf(t);
        const float w = t - t0f;
        const int t0 = (int)t0f;
        const float* row = sfb + a * DETN;
        const float v0 = ((unsigned)t0 < DETN)       ? row[t0]     : 0.0f;
        const float v1 = ((unsigned)(t0 + 1) < DETN) ? row[t0 + 1] : 0.0f;
        acc += v0 * (1.0f - w) + v1 * w;
    }
    red[tid] = acc;
    __syncthreads();
    if (tid < 64) {
        out[blockIdx.x * 64 + tid] =
            red[tid] + red[tid + 64] + red[tid + 128] + red[tid + 192];
    }
}

extern "C" void kernel_launch(void* const* d_in, const int* in_sizes, int n_in,
                              void* d_out, int out_size, void* d_ws, size_t ws_size,
                              hipStream_t stream) {
    const float* x      = (const float*)d_in[0];   // x_source (2,1,256,256)
    const float* st     = (const float*)d_in[1];   // s_target (2,1,362,45)
    const float* thetas = (const float*)d_in[2];   // thetas_deg (177)
    const int*   acq    = (const int*)d_in[3];     // acq_idx (45)
    float* out  = (float*)d_out;                   // (2,1,256,256) fp32
    float* wsf  = (float*)d_ws;
    float* sino = wsf + SINO_OFF;
    float* sf   = wsf + SF_OFF;

    dim3 gA(2 * NFULL, (DETN + 15) / 16);          // 354 x 23
    radon_kernel<<<gA, 128, 0, stream>>>(x, thetas, sino);
    dc_filter_kernel<<<2 * NFULL, 384, 0, stream>>>(sino, st, acq, sf);
    backproject_kernel<<<(2 * IMG * IMG) / 64, 256, 0, stream>>>(sf, thetas, out);
}